// Round 1
// baseline (2280.398 us; speedup 1.0000x reference)
//
#include <hip/hip_runtime.h>
#include <hip/hip_bf16.h>
#include <math.h>

#define BTOT 16384

__device__ __forceinline__ float selu_f(float x) {
  const float scale = 1.0507009873554805f;
  const float alpha = 1.6732632423543772f;
  return scale * (x > 0.0f ? x : alpha * expm1f(x));
}

// Y[b][n] = act( sum_{k<Kc} X[b][k]*W[k][n] + t[b]*W[Kc][n] + bias[n] )
// Tile: BM=128, BN=128, BK=32; 256 threads, 8x8 per thread, fp32.
template<bool DO_SELU>
__global__ __launch_bounds__(256) void mlp_layer_kernel(
    const float* __restrict__ X, int ldx, int Kc,
    const float* __restrict__ tvec,
    const float* __restrict__ W,     // [(Kc+1) x N]
    const float* __restrict__ bias,  // [N]
    float* __restrict__ Y, int N)
{
  __shared__ float sX[128][33];
  __shared__ float sW[32][128];
  const int tid = threadIdx.x;
  const int bm = blockIdx.x, bn = blockIdx.y;
  const int tx = tid & 15, ty = tid >> 4;
  const int rowbase = bm * 128, colbase = bn * 128;

  float acc[8][8];
  #pragma unroll
  for (int i = 0; i < 8; ++i)
    #pragma unroll
    for (int j = 0; j < 8; ++j) acc[i][j] = 0.0f;

  for (int k0 = 0; k0 < Kc; k0 += 32) {
    // load X tile 128x32
    {
      const int r0 = tid >> 3;
      const int kc = (tid & 7) << 2;
      #pragma unroll
      for (int pp = 0; pp < 4; ++pp) {
        int r = r0 + pp * 32;
        float4 v = *reinterpret_cast<const float4*>(
            X + (size_t)(rowbase + r) * ldx + k0 + kc);
        sX[r][kc + 0] = v.x; sX[r][kc + 1] = v.y;
        sX[r][kc + 2] = v.z; sX[r][kc + 3] = v.w;
      }
    }
    // load W tile 32x128
    {
      const int kk0 = tid >> 5;
      const int cc = (tid & 31) << 2;
      #pragma unroll
      for (int pp = 0; pp < 4; ++pp) {
        int kk = kk0 + pp * 8;
        *reinterpret_cast<float4*>(&sW[kk][cc]) =
            *reinterpret_cast<const float4*>(W + (size_t)(k0 + kk) * N + colbase + cc);
      }
    }
    __syncthreads();
    #pragma unroll
    for (int kk = 0; kk < 32; ++kk) {
      float a[8], b[8];
      #pragma unroll
      for (int i = 0; i < 8; ++i) a[i] = sX[ty * 8 + i][kk];
      float4 bv0 = *reinterpret_cast<const float4*>(&sW[kk][tx * 8]);
      float4 bv1 = *reinterpret_cast<const float4*>(&sW[kk][tx * 8 + 4]);
      b[0] = bv0.x; b[1] = bv0.y; b[2] = bv0.z; b[3] = bv0.w;
      b[4] = bv1.x; b[5] = bv1.y; b[6] = bv1.z; b[7] = bv1.w;
      #pragma unroll
      for (int i = 0; i < 8; ++i)
        #pragma unroll
        for (int j = 0; j < 8; ++j) acc[i][j] = fmaf(a[i], b[j], acc[i][j]);
    }
    __syncthreads();
  }

  // epilogue: t-term + bias + act + store
  float4 wl0 = *reinterpret_cast<const float4*>(W + (size_t)Kc * N + colbase + tx * 8);
  float4 wl1 = *reinterpret_cast<const float4*>(W + (size_t)Kc * N + colbase + tx * 8 + 4);
  float4 bb0 = *reinterpret_cast<const float4*>(bias + colbase + tx * 8);
  float4 bb1 = *reinterpret_cast<const float4*>(bias + colbase + tx * 8 + 4);
  float wl[8] = {wl0.x, wl0.y, wl0.z, wl0.w, wl1.x, wl1.y, wl1.z, wl1.w};
  float bb[8] = {bb0.x, bb0.y, bb0.z, bb0.w, bb1.x, bb1.y, bb1.z, bb1.w};
  #pragma unroll
  for (int i = 0; i < 8; ++i) {
    int row = rowbase + ty * 8 + i;
    float tv = tvec[row];
    float o[8];
    #pragma unroll
    for (int j = 0; j < 8; ++j) {
      float v = acc[i][j] + tv * wl[j] + bb[j];
      o[j] = DO_SELU ? selu_f(v) : v;
    }
    float4* dst = reinterpret_cast<float4*>(Y + (size_t)row * N + colbase + tx * 8);
    dst[0] = make_float4(o[0], o[1], o[2], o[3]);
    dst[1] = make_float4(o[4], o[5], o[6], o[7]);
  }
}

// One 32x32 matrix per 32-lane half-wave; lane i owns row i.
// expm via scaling (theta=0.5) + order-8 Taylor + squaring. All in-wave,
// LDS only for row-broadcast; no __syncthreads (avoids divergent barriers).
__global__ __launch_bounds__(256) void expm_kernel(
    const float* __restrict__ flat,   // [B,1024]
    const float* __restrict__ q,      // [B,32]
    const float* __restrict__ dtp,    // [1]
    float* __restrict__ out_q,        // [B,32]
    float* __restrict__ out_dlogp)    // [B]
{
  __shared__ float S[8][32][32];
  const int tid = threadIdx.x;
  const int g = tid >> 5;
  const int lane = tid & 31;
  const int m = blockIdx.x * 8 + g;
  const float dt = dtp[0];

  float A[32];
  {
    const float* fr = flat + (size_t)m * 1024 + lane * 32;
    #pragma unroll
    for (int j4 = 0; j4 < 8; ++j4) {
      float4 v = *reinterpret_cast<const float4*>(fr + j4 * 4);
      A[j4 * 4 + 0] = dt * fminf(fmaxf(v.x, -20.f), 20.f);
      A[j4 * 4 + 1] = dt * fminf(fmaxf(v.y, -20.f), 20.f);
      A[j4 * 4 + 2] = dt * fminf(fmaxf(v.z, -20.f), 20.f);
      A[j4 * 4 + 3] = dt * fminf(fmaxf(v.w, -20.f), 20.f);
    }
  }

  // dlogp = trace(A) (A already includes dt)
  float tr = A[lane];
  #pragma unroll
  for (int off = 1; off < 32; off <<= 1) tr += __shfl_xor(tr, off);
  if (lane == 0) out_dlogp[m] = tr;

  // stage A in LDS, compute 1-norm (max column abs-sum)
  #pragma unroll
  for (int j4 = 0; j4 < 8; ++j4)
    *reinterpret_cast<float4*>(&S[g][lane][j4 * 4]) =
        make_float4(A[j4 * 4], A[j4 * 4 + 1], A[j4 * 4 + 2], A[j4 * 4 + 3]);
  asm volatile("s_waitcnt lgkmcnt(0)" ::: "memory");
  float cs = 0.f;
  #pragma unroll
  for (int i = 0; i < 32; ++i) cs += fabsf(S[g][i][lane]);
  float nrm = cs;
  #pragma unroll
  for (int off = 1; off < 32; off <<= 1) nrm = fmaxf(nrm, __shfl_xor(nrm, off));

  int s = 0;
  if (nrm > 0.5f) {
    s = (int)ceilf(log2f(nrm) + 1.0f);   // ceil(log2(nrm/0.5))
    if (s < 0) s = 0;
    if (s > 24) s = 24;
  }
  const float sc = exp2f(-(float)s);
  #pragma unroll
  for (int j = 0; j < 32; ++j) A[j] *= sc;
  #pragma unroll
  for (int j4 = 0; j4 < 8; ++j4)
    *reinterpret_cast<float4*>(&S[g][lane][j4 * 4]) =
        make_float4(A[j4 * 4], A[j4 * 4 + 1], A[j4 * 4 + 2], A[j4 * 4 + 3]);
  asm volatile("s_waitcnt lgkmcnt(0)" ::: "memory");

  // Taylor: E = I + A + A^2/2! + ... + A^8/8!
  float E[32], T[32];
  #pragma unroll
  for (int j = 0; j < 32; ++j) { T[j] = A[j]; E[j] = A[j] + (j == lane ? 1.f : 0.f); }

  for (int k = 2; k <= 8; ++k) {   // runtime loop; inner fully unrolled (static reg idx)
    float Tn[32];
    #pragma unroll
    for (int j = 0; j < 32; ++j) Tn[j] = 0.f;
    #pragma unroll
    for (int kk = 0; kk < 32; ++kk) {
      float tv = T[kk];
      #pragma unroll
      for (int j4 = 0; j4 < 8; ++j4) {
        float4 sr = *reinterpret_cast<const float4*>(&S[g][kk][j4 * 4]);
        Tn[j4 * 4 + 0] = fmaf(tv, sr.x, Tn[j4 * 4 + 0]);
        Tn[j4 * 4 + 1] = fmaf(tv, sr.y, Tn[j4 * 4 + 1]);
        Tn[j4 * 4 + 2] = fmaf(tv, sr.z, Tn[j4 * 4 + 2]);
        Tn[j4 * 4 + 3] = fmaf(tv, sr.w, Tn[j4 * 4 + 3]);
      }
    }
    const float inv = 1.0f / (float)k;
    #pragma unroll
    for (int j = 0; j < 32; ++j) { T[j] = Tn[j] * inv; E[j] += T[j]; }
  }

  // squaring: E = E^(2^s)
  for (int it = 0; it < s; ++it) {
    #pragma unroll
    for (int j4 = 0; j4 < 8; ++j4)
      *reinterpret_cast<float4*>(&S[g][lane][j4 * 4]) =
          make_float4(E[j4 * 4], E[j4 * 4 + 1], E[j4 * 4 + 2], E[j4 * 4 + 3]);
    asm volatile("s_waitcnt lgkmcnt(0)" ::: "memory");
    float En[32];
    #pragma unroll
    for (int j = 0; j < 32; ++j) En[j] = 0.f;
    #pragma unroll
    for (int kk = 0; kk < 32; ++kk) {
      float ev = E[kk];
      #pragma unroll
      for (int j4 = 0; j4 < 8; ++j4) {
        float4 sr = *reinterpret_cast<const float4*>(&S[g][kk][j4 * 4]);
        En[j4 * 4 + 0] = fmaf(ev, sr.x, En[j4 * 4 + 0]);
        En[j4 * 4 + 1] = fmaf(ev, sr.y, En[j4 * 4 + 1]);
        En[j4 * 4 + 2] = fmaf(ev, sr.z, En[j4 * 4 + 2]);
        En[j4 * 4 + 3] = fmaf(ev, sr.w, En[j4 * 4 + 3]);
      }
    }
    #pragma unroll
    for (int j = 0; j < 32; ++j) E[j] = En[j];
    asm volatile("s_waitcnt lgkmcnt(0)" ::: "memory");
  }

  // new_q[lane] = sum_j E[lane][j] * q[m][j]
  const float* qr = q + (size_t)m * 32;
  float nq = 0.f;
  #pragma unroll
  for (int j4 = 0; j4 < 8; ++j4) {
    float4 qv = *reinterpret_cast<const float4*>(qr + j4 * 4);
    nq = fmaf(E[j4 * 4 + 0], qv.x, nq);
    nq = fmaf(E[j4 * 4 + 1], qv.y, nq);
    nq = fmaf(E[j4 * 4 + 2], qv.z, nq);
    nq = fmaf(E[j4 * 4 + 3], qv.w, nq);
  }
  out_q[(size_t)m * 32 + lane] = nq;
}

extern "C" void kernel_launch(void* const* d_in, const int* in_sizes, int n_in,
                              void* d_out, int out_size, void* d_ws, size_t ws_size,
                              hipStream_t stream) {
  const float* q    = (const float*)d_in[0];
  const float* p    = (const float*)d_in[1];
  const float* t    = (const float*)d_in[2];
  const float* dt   = (const float*)d_in[3];
  const float* W0   = (const float*)d_in[4];
  const float* b0   = (const float*)d_in[5];
  const float* W1   = (const float*)d_in[6];
  const float* b1   = (const float*)d_in[7];
  const float* W2   = (const float*)d_in[8];
  const float* b2   = (const float*)d_in[9];
  const float* W3   = (const float*)d_in[10];
  const float* b3   = (const float*)d_in[11];
  const float* Wout = (const float*)d_in[12];
  const float* bout = (const float*)d_in[13];

  float* ws   = (float*)d_ws;
  float* h1   = ws;                            // B*512
  float* h2   = ws + (size_t)BTOT * 512;       // B*512
  float* flat = ws + (size_t)2 * BTOT * 512;   // B*1024

  dim3 blk(256);
  dim3 gH(BTOT / 128, 512 / 128);
  dim3 gO(BTOT / 128, 1024 / 128);

  mlp_layer_kernel<true ><<<gH, blk, 0, stream>>>(p,  32,  32,  t, W0,   b0,   h1,   512);
  mlp_layer_kernel<true ><<<gH, blk, 0, stream>>>(h1, 512, 512, t, W1,   b1,   h2,   512);
  mlp_layer_kernel<true ><<<gH, blk, 0, stream>>>(h2, 512, 512, t, W2,   b2,   h1,   512);
  mlp_layer_kernel<true ><<<gH, blk, 0, stream>>>(h1, 512, 512, t, W3,   b3,   h2,   512);
  mlp_layer_kernel<false><<<gO, blk, 0, stream>>>(h2, 512, 512, t, Wout, bout, flat, 1024);

  float* out_q     = (float*)d_out;
  float* out_dlogp = out_q + (size_t)BTOT * 32;
  expm_kernel<<<BTOT / 8, blk, 0, stream>>>(flat, q, dt, out_q, out_dlogp);
}